// Round 9
// baseline (184.776 us; speedup 1.0000x reference)
//
#include <hip/hip_runtime.h>

#define G_    32
#define N_    128
#define NP1_  129
#define H_    32
#define EAD_  16
#define MAXD_ 5
#define NE_   65536
#define NPTH_ 1048576

// round-to-nearest-even f32 -> bf16 bits
static __device__ __forceinline__ unsigned int f2bf(float f) {
  unsigned int u = __float_as_uint(f);
  u += 0x7fffu + ((u >> 16) & 1u);
  return u >> 16;
}

// ---------------------------------------------------------------------------
// Kernel 1: edge encoder into compact eaval[NE][H]; edge_map[(g,i,j)] = e+1.
// ---------------------------------------------------------------------------
__global__ __launch_bounds__(256) void edge_encode_kernel(
    const float* __restrict__ edge_attr,    // [NE][16]
    const int*   __restrict__ edge_index,   // [3][NE]
    const float* __restrict__ edge_enc_w,   // [H][16]
    float*       __restrict__ eaval,        // [NE][H]
    int*         __restrict__ edge_map) {   // [G][N][N], e+1 (0 = empty)
  int t = blockIdx.x * blockDim.x + threadIdx.x;
  if (t >= NE_ * H_) return;
  int e = t >> 5;
  int h = t & 31;
  const float* ea = edge_attr + e * EAD_;
  const float* w  = edge_enc_w + h * EAD_;
  float s = 0.f;
#pragma unroll
  for (int k = 0; k < EAD_; ++k) s += ea[k] * w[k];
  eaval[t] = s;
  if (h == 0) {
    int g = edge_index[e];
    int i = edge_index[NE_ + e];
    int j = edge_index[2 * NE_ + e];
    edge_map[(g * N_ + i) * N_ + j] = e + 1;
  }
}

// ---------------------------------------------------------------------------
// Kernel 2: destination-organized path scatter. 1 thread per path; probe
// edge_map (2MB, L2); survivors store e+1 into slot[G][N][N][D] (unique).
// ---------------------------------------------------------------------------
__global__ __launch_bounds__(256) void path_scatter_kernel(
    const int* __restrict__ path_index,     // [6][NPTH]
    const int* __restrict__ edge_map,       // [G][N][N]
    int*       __restrict__ slot) {         // [G][N][N][MAXD]
  int p = blockIdx.x * blockDim.x + threadIdx.x;
  int pg = path_index[p];
  int pi = path_index[NPTH_ + p];
  int pj = path_index[2 * NPTH_ + p];
  int pd = path_index[3 * NPTH_ + p];
  int ps = path_index[4 * NPTH_ + p];
  int pt = path_index[5 * NPTH_ + p];
  int m = edge_map[(pg * N_ + ps) * N_ + pt];
  if (m) {
    slot[((pg * N_ + pi) * N_ + pj) * MAXD_ + pd] = m;
  }
}

// ---------------------------------------------------------------------------
// Kernel 3: PURE STREAMING mix. One thread per (cell, h) output element.
// No LDS, no barriers, no atomics. Half-wave shares a cell: slot loads and
// eaval-row loads are half-wave-uniform (HW broadcast, L1-hot); Wd is
// L1-resident (20KB). Sequential d-loop -> deterministic sum order.
// valmid[cell][h] bf16, consecutive threads -> 128B/wave coalesced stores.
// ---------------------------------------------------------------------------
__global__ __launch_bounds__(256) void mixval_kernel(
    const int*   __restrict__ slot,         // [G*N*N][MAXD]
    const int*   __restrict__ spatial_pos,  // [G*N*N]
    const float* __restrict__ spe,          // [512][H]
    const float* __restrict__ eaval,        // [NE][H]
    const float* __restrict__ Wdis,         // [d][h][k]
    unsigned short* __restrict__ valmid) {  // [G*N*N][H] bf16
  int idx  = blockIdx.x * blockDim.x + threadIdx.x;   // exact grid, no guard
  int h    = idx & 31;
  int cell = idx >> 5;
  const int* srow = slot + (size_t)cell * MAXD_;
  float acc = 0.f;
#pragma unroll
  for (int d = 0; d < MAXD_; ++d) {
    int m = srow[d];                        // half-wave broadcast, L1
    if (m) {                                // uniform within half-wave
      const float* ea = eaval + (size_t)(m - 1) * H_;  // uniform row
      const float* Wd = Wdis + d * (H_ * H_);          // L1-resident
      float v0 = 0.f, v1 = 0.f, v2 = 0.f, v3 = 0.f;
#pragma unroll
      for (int hh = 0; hh < H_; hh += 4) {
        v0 += ea[hh + 0] * Wd[(hh + 0) * H_ + h];
        v1 += ea[hh + 1] * Wd[(hh + 1) * H_ + h];
        v2 += ea[hh + 2] * Wd[(hh + 2) * H_ + h];
        v3 += ea[hh + 3] * Wd[(hh + 3) * H_ + h];
      }
      acc += (v0 + v1) + (v2 + v3);
    }
  }
  int s = spatial_pos[cell];                // half-wave broadcast
  int s2 = (s == 0) ? 1 : s;
  s2 = (s2 > 1) ? s2 - 1 : s2;
  s2 = (s2 > MAXD_) ? MAXD_ : s2;
  float inv = (s2 == 1) ? 1.0f
            : (s2 == 2) ? 0.5f
            : (s2 == 3) ? (1.0f / 3.0f)
            : (s2 == 4) ? 0.25f : 0.2f;
  float val = spe[s * H_ + h] + acc * inv;  // one 128B line per half-wave
  valmid[idx] = (unsigned short)f2bf(val);
}

// ---------------------------------------------------------------------------
// Kernel 4: output transpose + assembly. One block per (g, a) row.
// Phase A: vectorized uint4 loads of the 8KB bf16 valmid row -> padded LDS
//          (NO gathers — spe/inv already folded by mixval).
// Phase B: out[g][h][a][:] = 2*ab + (b==0 ? virt : lds), NT scalar stores.
// ---------------------------------------------------------------------------
__global__ __launch_bounds__(256) void output_kernel(
    const float* __restrict__ attn_bias,      // [G][129][129]
    const float* __restrict__ virt,           // [H]
    const unsigned short* __restrict__ valmid,// [G*N*N][H] bf16
    float* __restrict__ out) {                // [G][H][129][129]
  __shared__ float lds_val[N_ * 33];          // padded transpose tile
  __shared__ float lds_virt[H_];

  int blk = blockIdx.x;
  int g = blk / NP1_;
  int a = blk - g * NP1_;
  int tid = threadIdx.x;

  if (tid < H_) lds_virt[tid] = virt[tid];

  const float* ab = attn_bias + (g * NP1_ + a) * NP1_;

  if (a == 0) {
    __syncthreads();
    for (int t = tid; t < H_ * NP1_; t += 256) {
      int h = t / NP1_;
      int b = t - h * NP1_;
      __builtin_nontemporal_store(
          2.f * ab[b] + lds_virt[h],
          &out[((g * H_ + h) * NP1_) * NP1_ + b]);
    }
    return;
  }

  int i = a - 1;
  const uint4* vrow =
      (const uint4*)(valmid + (size_t)(g * N_ + i) * N_ * H_);  // 8KB row

  // phase A: 512 x 16B loads (8 bf16 each), 2 per thread, unpack to LDS
  for (int u = tid; u < 512; u += 256) {
    uint4 w = vrow[u];
    int base = u * 8;                         // element = j*32 + h
    unsigned int ws[4] = {w.x, w.y, w.z, w.w};
#pragma unroll
    for (int q = 0; q < 4; ++q) {
      int el = base + q * 2;
      int j  = el >> 5;
      int hh = el & 31;                       // even, hh+1 same j
      lds_val[j * 33 + hh]     = __uint_as_float((ws[q] & 0xFFFFu) << 16);
      lds_val[j * 33 + hh + 1] = __uint_as_float(ws[q] & 0xFFFF0000u);
    }
  }
  __syncthreads();

  // phase B: transposed LDS reads (2-way max = free), NT coalesced stores
  for (int t = tid; t < H_ * NP1_; t += 256) {
    int h = t / NP1_;
    int b = t - h * NP1_;
    float val = 2.f * ab[b];
    val += (b == 0) ? lds_virt[h] : lds_val[(b - 1) * 33 + h];
    __builtin_nontemporal_store(
        val, &out[((g * H_ + h) * NP1_ + a) * NP1_ + b]);
  }
}

// ---------------------------------------------------------------------------
extern "C" void kernel_launch(void* const* d_in, const int* in_sizes, int n_in,
                              void* d_out, int out_size, void* d_ws, size_t ws_size,
                              hipStream_t stream) {
  const float* attn_bias   = (const float*)d_in[0];
  const int*   spatial_pos = (const int*)d_in[1];
  const int*   edge_index  = (const int*)d_in[2];
  const float* edge_attr   = (const float*)d_in[3];
  const int*   path_index  = (const int*)d_in[4];
  const float* edge_enc_w  = (const float*)d_in[5];
  const float* spe         = (const float*)d_in[6];
  const float* virt        = (const float*)d_in[7];
  const float* edge_dis    = (const float*)d_in[8];
  float* out = (float*)d_out;

  const size_t SLOT_ELEMS = (size_t)G_ * N_ * N_ * MAXD_;  // 2.62M ints
  const size_t MAP_ELEMS  = (size_t)G_ * N_ * N_;          // 512K ints
  const size_t EAV_ELEMS  = (size_t)NE_ * H_;              // 2.1M floats

  int*            slot     = (int*)d_ws;
  int*            edge_map = slot + SLOT_ELEMS;
  float*          eaval    = (float*)(edge_map + MAP_ELEMS);
  unsigned short* valmid   = (unsigned short*)(eaval + EAV_ELEMS);  // 33.5MB

  // zero slot + edge_map (12.6MB); eaval/valmid fully overwritten each call
  hipMemsetAsync(slot, 0, (SLOT_ELEMS + MAP_ELEMS) * sizeof(int), stream);

  // edge encoder + map
  edge_encode_kernel<<<(NE_ * H_ + 255) / 256, 256, 0, stream>>>(
      edge_attr, edge_index, edge_enc_w, eaval, edge_map);
  // destination-organized path scatter
  path_scatter_kernel<<<NPTH_ / 256, 256, 0, stream>>>(
      path_index, edge_map, slot);
  // pure streaming mix -> bf16 valmid (16.7M threads, exact grid)
  mixval_kernel<<<(G_ * N_ * N_ * H_) / 256, 256, 0, stream>>>(
      slot, spatial_pos, spe, eaval, edge_dis, valmid);
  // output transpose + assembly
  output_kernel<<<G_ * NP1_, 256, 0, stream>>>(
      attn_bias, virt, valmid, out);
}

// Round 10
// 149.651 us; speedup vs baseline: 1.2347x; 1.2347x over previous
//
#include <hip/hip_runtime.h>

#define G_    32
#define N_    128
#define NP1_  129
#define H_    32
#define EAD_  16
#define MAXD_ 5
#define NE_   65536
#define NPTH_ 1048576

// round-to-nearest-even f32 -> bf16 bits
static __device__ __forceinline__ unsigned int f2bf(float f) {
  unsigned int u = __float_as_uint(f);
  u += 0x7fffu + ((u >> 16) & 1u);
  return u >> 16;
}
static __device__ __forceinline__ float bf2f(unsigned short v) {
  return __uint_as_float((unsigned int)v << 16);
}

// ---------------------------------------------------------------------------
// Kernel 1: edge encoder into compact eaval[NE][H]; edge_map[(g,i,j)] = e+1.
// ---------------------------------------------------------------------------
__global__ __launch_bounds__(256) void edge_encode_kernel(
    const float* __restrict__ edge_attr,    // [NE][16]
    const int*   __restrict__ edge_index,   // [3][NE]
    const float* __restrict__ edge_enc_w,   // [H][16]
    float*       __restrict__ eaval,        // [NE][H]
    int*         __restrict__ edge_map) {   // [G][N][N], e+1 (0 = empty)
  int t = blockIdx.x * blockDim.x + threadIdx.x;
  if (t >= NE_ * H_) return;
  int e = t >> 5;
  int h = t & 31;
  const float* ea = edge_attr + e * EAD_;
  const float* w  = edge_enc_w + h * EAD_;
  float s = 0.f;
#pragma unroll
  for (int k = 0; k < EAD_; ++k) s += ea[k] * w[k];
  eaval[t] = s;
  if (h == 0) {
    int g = edge_index[e];
    int i = edge_index[NE_ + e];
    int j = edge_index[2 * NE_ + e];
    edge_map[(g * N_ + i) * N_ + j] = e + 1;
  }
}

// ---------------------------------------------------------------------------
// Kernel 2: destination-organized path scatter. 1 thread per path; probe
// edge_map (2MB, L2); survivors store e+1 into slot[G][N][N][D] (unique).
// ---------------------------------------------------------------------------
__global__ __launch_bounds__(256) void path_scatter_kernel(
    const int* __restrict__ path_index,     // [6][NPTH]
    const int* __restrict__ edge_map,       // [G][N][N]
    int*       __restrict__ slot) {         // [G][N][N][MAXD]
  int p = blockIdx.x * blockDim.x + threadIdx.x;
  int pg = path_index[p];
  int pi = path_index[NPTH_ + p];
  int pj = path_index[2 * NPTH_ + p];
  int pd = path_index[3 * NPTH_ + p];
  int ps = path_index[4 * NPTH_ + p];
  int pt = path_index[5 * NPTH_ + p];
  int m = edge_map[(pg * N_ + ps) * N_ + pt];
  if (m) {
    slot[((pg * N_ + pi) * N_ + pj) * MAXD_ + pd] = m;
  }
}

// ---------------------------------------------------------------------------
// Kernel 3: DENSE regular mix precompute over all (e,d) combos.
// Thread = (d, e): t = d*NE + e, so a wave shares d and covers 64 edges.
// Wd[d] staged in LDS (4KB, wave-uniform b128 broadcasts, conflict-free);
// eaval row in registers (8 x float4); 1024 FMA; bf16-pack 4 uint4 stores.
// Zero divergence, zero dependence on path data.
// ---------------------------------------------------------------------------
__global__ __launch_bounds__(256) void mix_edge_kernel(
    const float* __restrict__ eaval,        // [NE][H]
    const float* __restrict__ Wdis,         // [d][h][k]
    unsigned short* __restrict__ mixede) {  // [d][NE][H] bf16
  __shared__ float wd_lds[H_ * H_];         // this block's d (4KB)
  int t = blockIdx.x * blockDim.x + threadIdx.x;
  int d = t >> 16;                          // NE = 65536
  int e = t & 0xFFFF;

  for (int u = threadIdx.x; u < H_ * H_; u += 256)
    wd_lds[u] = Wdis[d * (H_ * H_) + u];
  __syncthreads();

  float ea[H_];
  const float4* ear = (const float4*)(eaval + (size_t)e * H_);
#pragma unroll
  for (int q = 0; q < 8; ++q) {
    float4 v = ear[q];
    ea[q * 4 + 0] = v.x; ea[q * 4 + 1] = v.y;
    ea[q * 4 + 2] = v.z; ea[q * 4 + 3] = v.w;
  }

  float acc[H_];
#pragma unroll
  for (int k = 0; k < H_; ++k) acc[k] = 0.f;
#pragma unroll
  for (int h = 0; h < H_; ++h) {
    float a = ea[h];
#pragma unroll
    for (int k = 0; k < H_; ++k) acc[k] += a * wd_lds[h * H_ + k];
  }

  unsigned int pk[H_ / 2];
#pragma unroll
  for (int q = 0; q < H_ / 2; ++q)
    pk[q] = f2bf(acc[2 * q]) | (f2bf(acc[2 * q + 1]) << 16);
  uint4* dst = (uint4*)(mixede + (size_t)t * H_);
#pragma unroll
  for (int q = 0; q < 4; ++q)
    dst[q] = make_uint4(pk[4 * q], pk[4 * q + 1], pk[4 * q + 2], pk[4 * q + 3]);
}

// ---------------------------------------------------------------------------
// Kernel 4: streaming fold. Thread = (cell, h); half-wave shares a cell.
// 5 independent slot loads, then <=5 INDEPENDENT coalesced 64B row-gathers
// from mixede (no mix math here), + spe + normalizer -> valmid bf16.
// Chain depth 2; all long-latency loads in flight together.
// ---------------------------------------------------------------------------
__global__ __launch_bounds__(256) void mixfold_kernel(
    const int*   __restrict__ slot,         // [G*N*N][MAXD]
    const int*   __restrict__ spatial_pos,  // [G*N*N]
    const float* __restrict__ spe,          // [512][H]
    const unsigned short* __restrict__ mixede, // [d][NE][H] bf16
    unsigned short* __restrict__ valmid) {  // [G*N*N][H] bf16
  int idx  = blockIdx.x * blockDim.x + threadIdx.x;   // exact grid
  int h    = idx & 31;
  int cell = idx >> 5;
  const int* srow = slot + (size_t)cell * MAXD_;
  int m[MAXD_];
#pragma unroll
  for (int d = 0; d < MAXD_; ++d) m[d] = srow[d];     // independent, L1-bcast
  float acc = 0.f;
#pragma unroll
  for (int d = 0; d < MAXD_; ++d) {
    if (m[d]) {                                       // half-wave-uniform
      acc += bf2f(mixede[((size_t)d * NE_ + (m[d] - 1)) * H_ + h]);
    }
  }
  int s = spatial_pos[cell];                          // half-wave broadcast
  int s2 = (s == 0) ? 1 : s;
  s2 = (s2 > 1) ? s2 - 1 : s2;
  s2 = (s2 > MAXD_) ? MAXD_ : s2;
  float inv = (s2 == 1) ? 1.0f
            : (s2 == 2) ? 0.5f
            : (s2 == 3) ? (1.0f / 3.0f)
            : (s2 == 4) ? 0.25f : 0.2f;
  float val = spe[s * H_ + h] + acc * inv;            // coalesced 128B row
  valmid[idx] = (unsigned short)f2bf(val);
}

// ---------------------------------------------------------------------------
// Kernel 5: output transpose + assembly. One block per (g, a) row.
// Phase A: vectorized uint4 loads of the 8KB bf16 valmid row -> padded LDS.
// Phase B: out[g][h][a][:] = 2*ab + (b==0 ? virt : lds), NT stores.
// ---------------------------------------------------------------------------
__global__ __launch_bounds__(256) void output_kernel(
    const float* __restrict__ attn_bias,      // [G][129][129]
    const float* __restrict__ virt,           // [H]
    const unsigned short* __restrict__ valmid,// [G*N*N][H] bf16
    float* __restrict__ out) {                // [G][H][129][129]
  __shared__ float lds_val[N_ * 33];          // padded transpose tile
  __shared__ float lds_virt[H_];

  int blk = blockIdx.x;
  int g = blk / NP1_;
  int a = blk - g * NP1_;
  int tid = threadIdx.x;

  if (tid < H_) lds_virt[tid] = virt[tid];

  const float* ab = attn_bias + (g * NP1_ + a) * NP1_;

  if (a == 0) {
    __syncthreads();
    for (int t = tid; t < H_ * NP1_; t += 256) {
      int h = t / NP1_;
      int b = t - h * NP1_;
      __builtin_nontemporal_store(
          2.f * ab[b] + lds_virt[h],
          &out[((g * H_ + h) * NP1_) * NP1_ + b]);
    }
    return;
  }

  int i = a - 1;
  const uint4* vrow =
      (const uint4*)(valmid + (size_t)(g * N_ + i) * N_ * H_);  // 8KB row

  // phase A: 512 x 16B loads (8 bf16 each), 2 per thread, unpack to LDS
  for (int u = tid; u < 512; u += 256) {
    uint4 w = vrow[u];
    int base = u * 8;                         // element = j*32 + h
    unsigned int ws[4] = {w.x, w.y, w.z, w.w};
#pragma unroll
    for (int q = 0; q < 4; ++q) {
      int el = base + q * 2;
      int j  = el >> 5;
      int hh = el & 31;                       // even, hh+1 same j
      lds_val[j * 33 + hh]     = __uint_as_float((ws[q] & 0xFFFFu) << 16);
      lds_val[j * 33 + hh + 1] = __uint_as_float(ws[q] & 0xFFFF0000u);
    }
  }
  __syncthreads();

  // phase B: transposed LDS reads (2-way max = free), NT coalesced stores
  for (int t = tid; t < H_ * NP1_; t += 256) {
    int h = t / NP1_;
    int b = t - h * NP1_;
    float val = 2.f * ab[b];
    val += (b == 0) ? lds_virt[h] : lds_val[(b - 1) * 33 + h];
    __builtin_nontemporal_store(
        val, &out[((g * H_ + h) * NP1_ + a) * NP1_ + b]);
  }
}

// ---------------------------------------------------------------------------
extern "C" void kernel_launch(void* const* d_in, const int* in_sizes, int n_in,
                              void* d_out, int out_size, void* d_ws, size_t ws_size,
                              hipStream_t stream) {
  const float* attn_bias   = (const float*)d_in[0];
  const int*   spatial_pos = (const int*)d_in[1];
  const int*   edge_index  = (const int*)d_in[2];
  const float* edge_attr   = (const float*)d_in[3];
  const int*   path_index  = (const int*)d_in[4];
  const float* edge_enc_w  = (const float*)d_in[5];
  const float* spe         = (const float*)d_in[6];
  const float* virt        = (const float*)d_in[7];
  const float* edge_dis    = (const float*)d_in[8];
  float* out = (float*)d_out;

  const size_t SLOT_ELEMS = (size_t)G_ * N_ * N_ * MAXD_;  // 2.62M ints
  const size_t MAP_ELEMS  = (size_t)G_ * N_ * N_;          // 512K ints
  const size_t EAV_ELEMS  = (size_t)NE_ * H_;              // 2.1M floats
  const size_t MIX_ELEMS  = (size_t)MAXD_ * NE_ * H_;      // 10.5M ushorts

  int*            slot     = (int*)d_ws;
  int*            edge_map = slot + SLOT_ELEMS;
  float*          eaval    = (float*)(edge_map + MAP_ELEMS);
  unsigned short* mixede   = (unsigned short*)(eaval + EAV_ELEMS);   // 21MB
  unsigned short* valmid   = mixede + MIX_ELEMS;                     // 33.5MB

  // zero slot + edge_map (12.6MB); everything else fully overwritten
  hipMemsetAsync(slot, 0, (SLOT_ELEMS + MAP_ELEMS) * sizeof(int), stream);

  // edge encoder + map
  edge_encode_kernel<<<(NE_ * H_ + 255) / 256, 256, 0, stream>>>(
      edge_attr, edge_index, edge_enc_w, eaval, edge_map);
  // destination-organized path scatter
  path_scatter_kernel<<<NPTH_ / 256, 256, 0, stream>>>(
      path_index, edge_map, slot);
  // dense (e,d) mix precompute -> bf16 mixede
  mix_edge_kernel<<<(MAXD_ * NE_) / 256, 256, 0, stream>>>(
      eaval, edge_dis, mixede);
  // streaming fold -> bf16 valmid
  mixfold_kernel<<<(G_ * N_ * N_ * H_) / 256, 256, 0, stream>>>(
      slot, spatial_pos, spe, mixede, valmid);
  // output transpose + assembly
  output_kernel<<<G_ * NP1_, 256, 0, stream>>>(
      attn_bias, virt, valmid, out);
}

// Round 11
// 134.596 us; speedup vs baseline: 1.3728x; 1.1119x over previous
//
#include <hip/hip_runtime.h>

#define G_    32
#define N_    128
#define NP1_  129
#define H_    32
#define EAD_  16
#define MAXD_ 5
#define NE_   65536
#define NPTH_ 1048576

// round-to-nearest-even f32 -> bf16 bits
static __device__ __forceinline__ unsigned int f2bf(float f) {
  unsigned int u = __float_as_uint(f);
  u += 0x7fffu + ((u >> 16) & 1u);
  return u >> 16;
}
static __device__ __forceinline__ float bf2f(unsigned short v) {
  return __uint_as_float((unsigned int)v << 16);
}

// ---------------------------------------------------------------------------
// Kernel 1: edge encoder into compact eaval[NE][H]; edge_map[(g,i,j)] = e+1.
// ---------------------------------------------------------------------------
__global__ __launch_bounds__(256) void edge_encode_kernel(
    const float* __restrict__ edge_attr,    // [NE][16]
    const int*   __restrict__ edge_index,   // [3][NE]
    const float* __restrict__ edge_enc_w,   // [H][16]
    float*       __restrict__ eaval,        // [NE][H]
    int*         __restrict__ edge_map) {   // [G][N][N], e+1 (0 = empty)
  int t = blockIdx.x * blockDim.x + threadIdx.x;
  if (t >= NE_ * H_) return;
  int e = t >> 5;
  int h = t & 31;
  const float* ea = edge_attr + e * EAD_;
  const float* w  = edge_enc_w + h * EAD_;
  float s = 0.f;
#pragma unroll
  for (int k = 0; k < EAD_; ++k) s += ea[k] * w[k];
  eaval[t] = s;
  if (h == 0) {
    int g = edge_index[e];
    int i = edge_index[NE_ + e];
    int j = edge_index[2 * NE_ + e];
    edge_map[(g * N_ + i) * N_ + j] = e + 1;
  }
}

// ---------------------------------------------------------------------------
// Kernel 2: destination-organized path scatter. 1 thread per path; probe
// edge_map (2MB, L2); survivors store e+1 into slot[cell][d] (unique) and
// set flags[cell]=1 (benign race: all writers store 1).
// ---------------------------------------------------------------------------
__global__ __launch_bounds__(256) void path_scatter_kernel(
    const int* __restrict__ path_index,     // [6][NPTH]
    const int* __restrict__ edge_map,       // [G][N][N]
    int*       __restrict__ slot,           // [G*N*N][MAXD]
    unsigned char* __restrict__ flags) {    // [G*N*N]
  int p = blockIdx.x * blockDim.x + threadIdx.x;
  int pg = path_index[p];
  int pi = path_index[NPTH_ + p];
  int pj = path_index[2 * NPTH_ + p];
  int pd = path_index[3 * NPTH_ + p];
  int ps = path_index[4 * NPTH_ + p];
  int pt = path_index[5 * NPTH_ + p];
  int m = edge_map[(pg * N_ + ps) * N_ + pt];
  if (m) {
    int cell = (pg * N_ + pi) * N_ + pj;
    slot[(size_t)cell * MAXD_ + pd] = m;
    flags[cell] = 1;
  }
}

// ---------------------------------------------------------------------------
// Kernel 3: DENSE regular mix precompute over all (e,d) combos.
// Thread = (d, e): wave shares d, covers 64 edges. Wd in LDS (4KB),
// eaval row in registers, 1024 FMA, bf16-pack 4 uint4 stores.
// ---------------------------------------------------------------------------
__global__ __launch_bounds__(256) void mix_edge_kernel(
    const float* __restrict__ eaval,        // [NE][H]
    const float* __restrict__ Wdis,         // [d][h][k]
    unsigned short* __restrict__ mixede) {  // [d][NE][H] bf16
  __shared__ float wd_lds[H_ * H_];         // this block's d (4KB)
  int t = blockIdx.x * blockDim.x + threadIdx.x;
  int d = t >> 16;                          // NE = 65536
  int e = t & 0xFFFF;

  for (int u = threadIdx.x; u < H_ * H_; u += 256)
    wd_lds[u] = Wdis[d * (H_ * H_) + u];
  __syncthreads();

  float ea[H_];
  const float4* ear = (const float4*)(eaval + (size_t)e * H_);
#pragma unroll
  for (int q = 0; q < 8; ++q) {
    float4 v = ear[q];
    ea[q * 4 + 0] = v.x; ea[q * 4 + 1] = v.y;
    ea[q * 4 + 2] = v.z; ea[q * 4 + 3] = v.w;
  }

  float acc[H_];
#pragma unroll
  for (int k = 0; k < H_; ++k) acc[k] = 0.f;
#pragma unroll
  for (int h = 0; h < H_; ++h) {
    float a = ea[h];
#pragma unroll
    for (int k = 0; k < H_; ++k) acc[k] += a * wd_lds[h * H_ + k];
  }

  unsigned int pk[H_ / 2];
#pragma unroll
  for (int q = 0; q < H_ / 2; ++q)
    pk[q] = f2bf(acc[2 * q]) | (f2bf(acc[2 * q + 1]) << 16);
  uint4* dst = (uint4*)(mixede + (size_t)t * H_);
#pragma unroll
  for (int q = 0; q < 4; ++q)
    dst[q] = make_uint4(pk[4 * q], pk[4 * q + 1], pk[4 * q + 2], pk[4 * q + 3]);
}

// ---------------------------------------------------------------------------
// Kernel 4: streaming fold, 4-way ILP. Thread handles 4 (cell,h) elements
// spaced TOT/4 apart (same h -> coalesced stores per batch element).
// Empty cells (flag==0, ~78%): flag -> spe -> store; never touch slot.
// Hit cells: slot row (5 ints) + <=5 independent 64B mixede row-gathers.
// All 4 batch elements' load chains are independent -> 4x in-flight misses.
// ---------------------------------------------------------------------------
__global__ __launch_bounds__(256) void mixfold_kernel(
    const int*   __restrict__ slot,         // [G*N*N][MAXD]
    const unsigned char* __restrict__ flags,// [G*N*N]
    const int*   __restrict__ spatial_pos,  // [G*N*N]
    const float* __restrict__ spe,          // [512][H]
    const unsigned short* __restrict__ mixede, // [d][NE][H] bf16
    unsigned short* __restrict__ valmid) {  // [G*N*N][H] bf16
  const int TOT   = G_ * N_ * N_ * H_;      // 16.7M
  const int CHUNK = TOT / 4;                // 4.19M
  const int CCH   = CHUNK >> 5;             // 131072 cells per chunk
  int base = blockIdx.x * blockDim.x + threadIdx.x;   // exact grid = CHUNK
  int h  = base & 31;
  int c0 = base >> 5;

  int cells[4];
#pragma unroll
  for (int k = 0; k < 4; ++k) cells[k] = c0 + k * CCH;

  unsigned char fl[4];
  int sv[4];
#pragma unroll
  for (int k = 0; k < 4; ++k) fl[k] = flags[cells[k]];   // sequential stream
#pragma unroll
  for (int k = 0; k < 4; ++k) sv[k] = spatial_pos[cells[k]];

  float acc[4] = {0.f, 0.f, 0.f, 0.f};
#pragma unroll
  for (int k = 0; k < 4; ++k) {
    if (fl[k]) {                                    // half-wave-uniform
      const int* srow = slot + (size_t)cells[k] * MAXD_;
      int m[MAXD_];
#pragma unroll
      for (int d = 0; d < MAXD_; ++d) m[d] = srow[d];
#pragma unroll
      for (int d = 0; d < MAXD_; ++d) {
        if (m[d]) {
          acc[k] += bf2f(mixede[((size_t)d * NE_ + (m[d] - 1)) * H_ + h]);
        }
      }
    }
  }

#pragma unroll
  for (int k = 0; k < 4; ++k) {
    int s = sv[k];
    int s2 = (s == 0) ? 1 : s;
    s2 = (s2 > 1) ? s2 - 1 : s2;
    s2 = (s2 > MAXD_) ? MAXD_ : s2;
    float inv = (s2 == 1) ? 1.0f
              : (s2 == 2) ? 0.5f
              : (s2 == 3) ? (1.0f / 3.0f)
              : (s2 == 4) ? 0.25f : 0.2f;
    float val = spe[s * H_ + h] + acc[k] * inv;     // coalesced 128B row
    valmid[base + k * CHUNK] = (unsigned short)f2bf(val);
  }
}

// ---------------------------------------------------------------------------
// Kernel 5: output transpose + assembly. One block per (g, a) row.
// Phase A: vectorized uint4 loads of the 8KB bf16 valmid row -> padded LDS.
// Phase B: out[g][h][a][:] = 2*ab + (b==0 ? virt : lds), NT stores.
// ---------------------------------------------------------------------------
__global__ __launch_bounds__(256) void output_kernel(
    const float* __restrict__ attn_bias,      // [G][129][129]
    const float* __restrict__ virt,           // [H]
    const unsigned short* __restrict__ valmid,// [G*N*N][H] bf16
    float* __restrict__ out) {                // [G][H][129][129]
  __shared__ float lds_val[N_ * 33];          // padded transpose tile
  __shared__ float lds_virt[H_];

  int blk = blockIdx.x;
  int g = blk / NP1_;
  int a = blk - g * NP1_;
  int tid = threadIdx.x;

  if (tid < H_) lds_virt[tid] = virt[tid];

  const float* ab = attn_bias + (g * NP1_ + a) * NP1_;

  if (a == 0) {
    __syncthreads();
    for (int t = tid; t < H_ * NP1_; t += 256) {
      int h = t / NP1_;
      int b = t - h * NP1_;
      __builtin_nontemporal_store(
          2.f * ab[b] + lds_virt[h],
          &out[((g * H_ + h) * NP1_) * NP1_ + b]);
    }
    return;
  }

  int i = a - 1;
  const uint4* vrow =
      (const uint4*)(valmid + (size_t)(g * N_ + i) * N_ * H_);  // 8KB row

  // phase A: 512 x 16B loads (8 bf16 each), 2 per thread, unpack to LDS
  for (int u = tid; u < 512; u += 256) {
    uint4 w = vrow[u];
    int base = u * 8;                         // element = j*32 + h
    unsigned int ws[4] = {w.x, w.y, w.z, w.w};
#pragma unroll
    for (int q = 0; q < 4; ++q) {
      int el = base + q * 2;
      int j  = el >> 5;
      int hh = el & 31;                       // even, hh+1 same j
      lds_val[j * 33 + hh]     = __uint_as_float((ws[q] & 0xFFFFu) << 16);
      lds_val[j * 33 + hh + 1] = __uint_as_float(ws[q] & 0xFFFF0000u);
    }
  }
  __syncthreads();

  // phase B: transposed LDS reads (2-way max = free), NT coalesced stores
  for (int t = tid; t < H_ * NP1_; t += 256) {
    int h = t / NP1_;
    int b = t - h * NP1_;
    float val = 2.f * ab[b];
    val += (b == 0) ? lds_virt[h] : lds_val[(b - 1) * 33 + h];
    __builtin_nontemporal_store(
        val, &out[((g * H_ + h) * NP1_ + a) * NP1_ + b]);
  }
}

// ---------------------------------------------------------------------------
extern "C" void kernel_launch(void* const* d_in, const int* in_sizes, int n_in,
                              void* d_out, int out_size, void* d_ws, size_t ws_size,
                              hipStream_t stream) {
  const float* attn_bias   = (const float*)d_in[0];
  const int*   spatial_pos = (const int*)d_in[1];
  const int*   edge_index  = (const int*)d_in[2];
  const float* edge_attr   = (const float*)d_in[3];
  const int*   path_index  = (const int*)d_in[4];
  const float* edge_enc_w  = (const float*)d_in[5];
  const float* spe         = (const float*)d_in[6];
  const float* virt        = (const float*)d_in[7];
  const float* edge_dis    = (const float*)d_in[8];
  float* out = (float*)d_out;

  const size_t SLOT_ELEMS = (size_t)G_ * N_ * N_ * MAXD_;  // 2.62M ints
  const size_t MAP_ELEMS  = (size_t)G_ * N_ * N_;          // 512K ints
  const size_t FLAG_INTS  = (size_t)G_ * N_ * N_ / 4;      // 512KB as ints
  const size_t EAV_ELEMS  = (size_t)NE_ * H_;              // 2.1M floats
  const size_t MIX_ELEMS  = (size_t)MAXD_ * NE_ * H_;      // 10.5M ushorts

  int*            slot     = (int*)d_ws;
  int*            edge_map = slot + SLOT_ELEMS;
  unsigned char*  flags    = (unsigned char*)(edge_map + MAP_ELEMS);
  float*          eaval    = (float*)(edge_map + MAP_ELEMS + FLAG_INTS);
  unsigned short* mixede   = (unsigned short*)(eaval + EAV_ELEMS);   // 21MB
  unsigned short* valmid   = mixede + MIX_ELEMS;                     // 33.5MB

  // zero slot + edge_map + flags (13.1MB); everything else fully overwritten
  hipMemsetAsync(slot, 0, (SLOT_ELEMS + MAP_ELEMS + FLAG_INTS) * sizeof(int),
                 stream);

  // edge encoder + map
  edge_encode_kernel<<<(NE_ * H_ + 255) / 256, 256, 0, stream>>>(
      edge_attr, edge_index, edge_enc_w, eaval, edge_map);
  // destination-organized path scatter (+ per-cell flag)
  path_scatter_kernel<<<NPTH_ / 256, 256, 0, stream>>>(
      path_index, edge_map, slot, flags);
  // dense (e,d) mix precompute -> bf16 mixede
  mix_edge_kernel<<<(MAXD_ * NE_) / 256, 256, 0, stream>>>(
      eaval, edge_dis, mixede);
  // streaming fold (4-way ILP + flag short-circuit) -> bf16 valmid
  mixfold_kernel<<<(G_ * N_ * N_ * H_ / 4) / 256, 256, 0, stream>>>(
      slot, flags, spatial_pos, spe, mixede, valmid);
  // output transpose + assembly
  output_kernel<<<G_ * NP1_, 256, 0, stream>>>(
      attn_bias, virt, valmid, out);
}

// Round 12
// 132.303 us; speedup vs baseline: 1.3966x; 1.0173x over previous
//
#include <hip/hip_runtime.h>

#define G_    32
#define N_    128
#define NP1_  129
#define H_    32
#define EAD_  16
#define MAXD_ 5
#define NE_   65536
#define NPTH_ 1048576
#define ILP_  8      // mixfold batch factor

// round-to-nearest-even f32 -> bf16 bits
static __device__ __forceinline__ unsigned int f2bf(float f) {
  unsigned int u = __float_as_uint(f);
  u += 0x7fffu + ((u >> 16) & 1u);
  return u >> 16;
}
static __device__ __forceinline__ float bf2f(unsigned short v) {
  return __uint_as_float((unsigned int)v << 16);
}

// ---------------------------------------------------------------------------
// Kernel 1: edge encoder into compact eaval[NE][H]; edge_map[(g,i,j)] = e+1.
// ---------------------------------------------------------------------------
__global__ __launch_bounds__(256) void edge_encode_kernel(
    const float* __restrict__ edge_attr,    // [NE][16]
    const int*   __restrict__ edge_index,   // [3][NE]
    const float* __restrict__ edge_enc_w,   // [H][16]
    float*       __restrict__ eaval,        // [NE][H]
    int*         __restrict__ edge_map) {   // [G][N][N], e+1 (0 = empty)
  int t = blockIdx.x * blockDim.x + threadIdx.x;
  if (t >= NE_ * H_) return;
  int e = t >> 5;
  int h = t & 31;
  const float* ea = edge_attr + e * EAD_;
  const float* w  = edge_enc_w + h * EAD_;
  float s = 0.f;
#pragma unroll
  for (int k = 0; k < EAD_; ++k) s += ea[k] * w[k];
  eaval[t] = s;
  if (h == 0) {
    int g = edge_index[e];
    int i = edge_index[NE_ + e];
    int j = edge_index[2 * NE_ + e];
    edge_map[(g * N_ + i) * N_ + j] = e + 1;
  }
}

// ---------------------------------------------------------------------------
// Kernel 2: destination-organized path scatter. 1 thread per path; probe
// edge_map first (3 streams); load destination components ONLY on hit
// (12.5%) — saves ~8MB of fetch. Destinations unique -> plain stores.
// ---------------------------------------------------------------------------
__global__ __launch_bounds__(256) void path_scatter_kernel(
    const int* __restrict__ path_index,     // [6][NPTH]
    const int* __restrict__ edge_map,       // [G][N][N]
    int*       __restrict__ slot,           // [G*N*N][MAXD]
    unsigned char* __restrict__ flags) {    // [G*N*N]
  int p = blockIdx.x * blockDim.x + threadIdx.x;
  int pg = path_index[p];
  int ps = path_index[4 * NPTH_ + p];
  int pt = path_index[5 * NPTH_ + p];
  int m = edge_map[(pg * N_ + ps) * N_ + pt];
  if (m) {
    int pi = path_index[NPTH_ + p];
    int pj = path_index[2 * NPTH_ + p];
    int pd = path_index[3 * NPTH_ + p];
    int cell = (pg * N_ + pi) * N_ + pj;
    slot[(size_t)cell * MAXD_ + pd] = m;
    flags[cell] = 1;
  }
}

// ---------------------------------------------------------------------------
// Kernel 3: DENSE regular mix precompute over all (e,d) combos.
// Thread = (d, e): wave shares d, covers 64 edges. Wd in LDS (4KB),
// eaval row in registers, 1024 FMA, bf16-pack 4 uint4 stores.
// ---------------------------------------------------------------------------
__global__ __launch_bounds__(256) void mix_edge_kernel(
    const float* __restrict__ eaval,        // [NE][H]
    const float* __restrict__ Wdis,         // [d][h][k]
    unsigned short* __restrict__ mixede) {  // [d][NE][H] bf16
  __shared__ float wd_lds[H_ * H_];         // this block's d (4KB)
  int t = blockIdx.x * blockDim.x + threadIdx.x;
  int d = t >> 16;                          // NE = 65536
  int e = t & 0xFFFF;

  for (int u = threadIdx.x; u < H_ * H_; u += 256)
    wd_lds[u] = Wdis[d * (H_ * H_) + u];
  __syncthreads();

  float ea[H_];
  const float4* ear = (const float4*)(eaval + (size_t)e * H_);
#pragma unroll
  for (int q = 0; q < 8; ++q) {
    float4 v = ear[q];
    ea[q * 4 + 0] = v.x; ea[q * 4 + 1] = v.y;
    ea[q * 4 + 2] = v.z; ea[q * 4 + 3] = v.w;
  }

  float acc[H_];
#pragma unroll
  for (int k = 0; k < H_; ++k) acc[k] = 0.f;
#pragma unroll
  for (int h = 0; h < H_; ++h) {
    float a = ea[h];
#pragma unroll
    for (int k = 0; k < H_; ++k) acc[k] += a * wd_lds[h * H_ + k];
  }

  unsigned int pk[H_ / 2];
#pragma unroll
  for (int q = 0; q < H_ / 2; ++q)
    pk[q] = f2bf(acc[2 * q]) | (f2bf(acc[2 * q + 1]) << 16);
  uint4* dst = (uint4*)(mixede + (size_t)t * H_);
#pragma unroll
  for (int q = 0; q < 4; ++q)
    dst[q] = make_uint4(pk[4 * q], pk[4 * q + 1], pk[4 * q + 2], pk[4 * q + 3]);
}

// ---------------------------------------------------------------------------
// Kernel 4: streaming fold, 8-way ILP. Thread handles 8 (cell,h) elements
// spaced TOT/8 apart (same h -> coalesced stores per batch element).
// Empty cells (flag==0, ~78%): flag -> spe -> store; never touch slot.
// Hit cells: slot row (5 ints) + <=5 independent 64B mixede row-gathers.
// All 8 batch elements' load chains are independent -> 8x in-flight misses.
// ---------------------------------------------------------------------------
__global__ __launch_bounds__(256) void mixfold_kernel(
    const int*   __restrict__ slot,         // [G*N*N][MAXD]
    const unsigned char* __restrict__ flags,// [G*N*N]
    const int*   __restrict__ spatial_pos,  // [G*N*N]
    const float* __restrict__ spe,          // [512][H]
    const unsigned short* __restrict__ mixede, // [d][NE][H] bf16
    unsigned short* __restrict__ valmid) {  // [G*N*N][H] bf16
  const int TOT   = G_ * N_ * N_ * H_;      // 16.7M
  const int CHUNK = TOT / ILP_;             // 2.10M
  const int CCH   = CHUNK >> 5;             // 65536 cells per chunk
  int base = blockIdx.x * blockDim.x + threadIdx.x;   // exact grid = CHUNK
  int h  = base & 31;
  int c0 = base >> 5;

  int cells[ILP_];
#pragma unroll
  for (int k = 0; k < ILP_; ++k) cells[k] = c0 + k * CCH;

  unsigned char fl[ILP_];
  int sv[ILP_];
#pragma unroll
  for (int k = 0; k < ILP_; ++k) fl[k] = flags[cells[k]];  // sequential stream
#pragma unroll
  for (int k = 0; k < ILP_; ++k) sv[k] = spatial_pos[cells[k]];

  float acc[ILP_];
#pragma unroll
  for (int k = 0; k < ILP_; ++k) acc[k] = 0.f;
#pragma unroll
  for (int k = 0; k < ILP_; ++k) {
    if (fl[k]) {                                    // half-wave-uniform
      const int* srow = slot + (size_t)cells[k] * MAXD_;
      int m[MAXD_];
#pragma unroll
      for (int d = 0; d < MAXD_; ++d) m[d] = srow[d];
#pragma unroll
      for (int d = 0; d < MAXD_; ++d) {
        if (m[d]) {
          acc[k] += bf2f(mixede[((size_t)d * NE_ + (m[d] - 1)) * H_ + h]);
        }
      }
    }
  }

#pragma unroll
  for (int k = 0; k < ILP_; ++k) {
    int s = sv[k];
    int s2 = (s == 0) ? 1 : s;
    s2 = (s2 > 1) ? s2 - 1 : s2;
    s2 = (s2 > MAXD_) ? MAXD_ : s2;
    float inv = (s2 == 1) ? 1.0f
              : (s2 == 2) ? 0.5f
              : (s2 == 3) ? (1.0f / 3.0f)
              : (s2 == 4) ? 0.25f : 0.2f;
    float val = spe[s * H_ + h] + acc[k] * inv;     // coalesced 128B row
    valmid[base + k * CHUNK] = (unsigned short)f2bf(val);
  }
}

// ---------------------------------------------------------------------------
// Kernel 5: output transpose + assembly. One block per (g, a) row.
// Phase A: vectorized uint4 loads of the 8KB bf16 valmid row -> padded LDS.
// Phase B: out[g][h][a][:] = 2*ab + (b==0 ? virt : lds), NT stores.
// ---------------------------------------------------------------------------
__global__ __launch_bounds__(256) void output_kernel(
    const float* __restrict__ attn_bias,      // [G][129][129]
    const float* __restrict__ virt,           // [H]
    const unsigned short* __restrict__ valmid,// [G*N*N][H] bf16
    float* __restrict__ out) {                // [G][H][129][129]
  __shared__ float lds_val[N_ * 33];          // padded transpose tile
  __shared__ float lds_virt[H_];

  int blk = blockIdx.x;
  int g = blk / NP1_;
  int a = blk - g * NP1_;
  int tid = threadIdx.x;

  if (tid < H_) lds_virt[tid] = virt[tid];

  const float* ab = attn_bias + (g * NP1_ + a) * NP1_;

  if (a == 0) {
    __syncthreads();
    for (int t = tid; t < H_ * NP1_; t += 256) {
      int h = t / NP1_;
      int b = t - h * NP1_;
      __builtin_nontemporal_store(
          2.f * ab[b] + lds_virt[h],
          &out[((g * H_ + h) * NP1_) * NP1_ + b]);
    }
    return;
  }

  int i = a - 1;
  const uint4* vrow =
      (const uint4*)(valmid + (size_t)(g * N_ + i) * N_ * H_);  // 8KB row

  // phase A: 512 x 16B loads (8 bf16 each), 2 per thread, unpack to LDS
  for (int u = tid; u < 512; u += 256) {
    uint4 w = vrow[u];
    int base = u * 8;                         // element = j*32 + h
    unsigned int ws[4] = {w.x, w.y, w.z, w.w};
#pragma unroll
    for (int q = 0; q < 4; ++q) {
      int el = base + q * 2;
      int j  = el >> 5;
      int hh = el & 31;                       // even, hh+1 same j
      lds_val[j * 33 + hh]     = __uint_as_float((ws[q] & 0xFFFFu) << 16);
      lds_val[j * 33 + hh + 1] = __uint_as_float(ws[q] & 0xFFFF0000u);
    }
  }
  __syncthreads();

  // phase B: transposed LDS reads (2-way max = free), NT coalesced stores
  for (int t = tid; t < H_ * NP1_; t += 256) {
    int h = t / NP1_;
    int b = t - h * NP1_;
    float val = 2.f * ab[b];
    val += (b == 0) ? lds_virt[h] : lds_val[(b - 1) * 33 + h];
    __builtin_nontemporal_store(
        val, &out[((g * H_ + h) * NP1_ + a) * NP1_ + b]);
  }
}

// ---------------------------------------------------------------------------
extern "C" void kernel_launch(void* const* d_in, const int* in_sizes, int n_in,
                              void* d_out, int out_size, void* d_ws, size_t ws_size,
                              hipStream_t stream) {
  const float* attn_bias   = (const float*)d_in[0];
  const int*   spatial_pos = (const int*)d_in[1];
  const int*   edge_index  = (const int*)d_in[2];
  const float* edge_attr   = (const float*)d_in[3];
  const int*   path_index  = (const int*)d_in[4];
  const float* edge_enc_w  = (const float*)d_in[5];
  const float* spe         = (const float*)d_in[6];
  const float* virt        = (const float*)d_in[7];
  const float* edge_dis    = (const float*)d_in[8];
  float* out = (float*)d_out;

  const size_t SLOT_ELEMS = (size_t)G_ * N_ * N_ * MAXD_;  // 2.62M ints
  const size_t MAP_ELEMS  = (size_t)G_ * N_ * N_;          // 512K ints
  const size_t FLAG_INTS  = (size_t)G_ * N_ * N_ / 4;      // 512KB as ints
  const size_t EAV_ELEMS  = (size_t)NE_ * H_;              // 2.1M floats
  const size_t MIX_ELEMS  = (size_t)MAXD_ * NE_ * H_;      // 10.5M ushorts

  int*            slot     = (int*)d_ws;
  int*            edge_map = slot + SLOT_ELEMS;
  unsigned char*  flags    = (unsigned char*)(edge_map + MAP_ELEMS);
  float*          eaval    = (float*)(edge_map + MAP_ELEMS + FLAG_INTS);
  unsigned short* mixede   = (unsigned short*)(eaval + EAV_ELEMS);   // 21MB
  unsigned short* valmid   = mixede + MIX_ELEMS;                     // 33.5MB

  // zero slot + edge_map + flags (13.1MB); everything else fully overwritten
  hipMemsetAsync(slot, 0, (SLOT_ELEMS + MAP_ELEMS + FLAG_INTS) * sizeof(int),
                 stream);

  // edge encoder + map
  edge_encode_kernel<<<(NE_ * H_ + 255) / 256, 256, 0, stream>>>(
      edge_attr, edge_index, edge_enc_w, eaval, edge_map);
  // destination-organized path scatter (+ per-cell flag)
  path_scatter_kernel<<<NPTH_ / 256, 256, 0, stream>>>(
      path_index, edge_map, slot, flags);
  // dense (e,d) mix precompute -> bf16 mixede
  mix_edge_kernel<<<(MAXD_ * NE_) / 256, 256, 0, stream>>>(
      eaval, edge_dis, mixede);
  // streaming fold (8-way ILP + flag short-circuit) -> bf16 valmid
  mixfold_kernel<<<(G_ * N_ * N_ * H_ / ILP_) / 256, 256, 0, stream>>>(
      slot, flags, spatial_pos, spe, mixede, valmid);
  // output transpose + assembly
  output_kernel<<<G_ * NP1_, 256, 0, stream>>>(
      attn_bias, virt, valmid, out);
}

// Round 13
// 121.467 us; speedup vs baseline: 1.5212x; 1.0892x over previous
//
#include <hip/hip_runtime.h>

#define G_    32
#define N_    128
#define NP1_  129
#define H_    32
#define EAD_  16
#define MAXD_ 5
#define NE_   65536
#define NPTH_ 1048576

// round-to-nearest-even f32 -> bf16 bits
static __device__ __forceinline__ unsigned int f2bf(float f) {
  unsigned int u = __float_as_uint(f);
  u += 0x7fffu + ((u >> 16) & 1u);
  return u >> 16;
}
static __device__ __forceinline__ float bf2f(unsigned short v) {
  return __uint_as_float((unsigned int)v << 16);
}

// ---------------------------------------------------------------------------
// Kernel 0: fast zero-fill (hipMemsetAsync's fillBuffer ran at 0.32 TB/s /
// 8.5% occupancy = 40us for 13MB; this grid-stride uint4 version streams).
// ---------------------------------------------------------------------------
__global__ __launch_bounds__(256) void zero_fill_kernel(
    uint4* __restrict__ dst, int n16) {
  int idx = blockIdx.x * blockDim.x + threadIdx.x;
  int stride = gridDim.x * blockDim.x;
  const uint4 z = make_uint4(0u, 0u, 0u, 0u);
  for (int i = idx; i < n16; i += stride) dst[i] = z;
}

// ---------------------------------------------------------------------------
// Kernel 1: edge encoder into compact eaval[NE][H]; edge_map[(g,i,j)] = e+1.
// ---------------------------------------------------------------------------
__global__ __launch_bounds__(256) void edge_encode_kernel(
    const float* __restrict__ edge_attr,    // [NE][16]
    const int*   __restrict__ edge_index,   // [3][NE]
    const float* __restrict__ edge_enc_w,   // [H][16]
    float*       __restrict__ eaval,        // [NE][H]
    int*         __restrict__ edge_map) {   // [G][N][N], e+1 (0 = empty)
  int t = blockIdx.x * blockDim.x + threadIdx.x;
  if (t >= NE_ * H_) return;
  int e = t >> 5;
  int h = t & 31;
  const float* ea = edge_attr + e * EAD_;
  const float* w  = edge_enc_w + h * EAD_;
  float s = 0.f;
#pragma unroll
  for (int k = 0; k < EAD_; ++k) s += ea[k] * w[k];
  eaval[t] = s;
  if (h == 0) {
    int g = edge_index[e];
    int i = edge_index[NE_ + e];
    int j = edge_index[2 * NE_ + e];
    edge_map[(g * N_ + i) * N_ + j] = e + 1;
  }
}

// ---------------------------------------------------------------------------
// Kernel 2: destination-organized path scatter. 1 thread per path; probe
// edge_map first (3 streams); load destination components ONLY on hit.
// ---------------------------------------------------------------------------
__global__ __launch_bounds__(256) void path_scatter_kernel(
    const int* __restrict__ path_index,     // [6][NPTH]
    const int* __restrict__ edge_map,       // [G][N][N]
    int*       __restrict__ slot,           // [G*N*N][MAXD]
    unsigned char* __restrict__ flags) {    // [G*N*N]
  int p = blockIdx.x * blockDim.x + threadIdx.x;
  int pg = path_index[p];
  int ps = path_index[4 * NPTH_ + p];
  int pt = path_index[5 * NPTH_ + p];
  int m = edge_map[(pg * N_ + ps) * N_ + pt];
  if (m) {
    int pi = path_index[NPTH_ + p];
    int pj = path_index[2 * NPTH_ + p];
    int pd = path_index[3 * NPTH_ + p];
    int cell = (pg * N_ + pi) * N_ + pj;
    slot[(size_t)cell * MAXD_ + pd] = m;
    flags[cell] = 1;
  }
}

// ---------------------------------------------------------------------------
// Kernel 3: DENSE regular mix precompute over all (e,d) combos.
// Thread = (d, e): wave shares d, covers 64 edges. Wd in LDS (4KB),
// eaval row in registers, 1024 FMA, bf16-pack 4 uint4 stores.
// ---------------------------------------------------------------------------
__global__ __launch_bounds__(256) void mix_edge_kernel(
    const float* __restrict__ eaval,        // [NE][H]
    const float* __restrict__ Wdis,         // [d][h][k]
    unsigned short* __restrict__ mixede) {  // [d][NE][H] bf16
  __shared__ float wd_lds[H_ * H_];         // this block's d (4KB)
  int t = blockIdx.x * blockDim.x + threadIdx.x;
  int d = t >> 16;                          // NE = 65536
  int e = t & 0xFFFF;

  for (int u = threadIdx.x; u < H_ * H_; u += 256)
    wd_lds[u] = Wdis[d * (H_ * H_) + u];
  __syncthreads();

  float ea[H_];
  const float4* ear = (const float4*)(eaval + (size_t)e * H_);
#pragma unroll
  for (int q = 0; q < 8; ++q) {
    float4 v = ear[q];
    ea[q * 4 + 0] = v.x; ea[q * 4 + 1] = v.y;
    ea[q * 4 + 2] = v.z; ea[q * 4 + 3] = v.w;
  }

  float acc[H_];
#pragma unroll
  for (int k = 0; k < H_; ++k) acc[k] = 0.f;
#pragma unroll
  for (int h = 0; h < H_; ++h) {
    float a = ea[h];
#pragma unroll
    for (int k = 0; k < H_; ++k) acc[k] += a * wd_lds[h * H_ + k];
  }

  unsigned int pk[H_ / 2];
#pragma unroll
  for (int q = 0; q < H_ / 2; ++q)
    pk[q] = f2bf(acc[2 * q]) | (f2bf(acc[2 * q + 1]) << 16);
  uint4* dst = (uint4*)(mixede + (size_t)t * H_);
#pragma unroll
  for (int q = 0; q < 4; ++q)
    dst[q] = make_uint4(pk[4 * q], pk[4 * q + 1], pk[4 * q + 2], pk[4 * q + 3]);
}

// ---------------------------------------------------------------------------
// Kernel 4 (fused): per-row fold + transpose + assembly. Block per (g, a).
// Phase A: 8 half-waves x 16 cells (4-cell unrolled, lane = h). Per cell:
//   flag (uniform byte) -> [5 slot ints + <=5 independent 64B mixede
//   row-gathers] ; + spe row (uniform 128B) ; fold -> padded LDS tile.
//   No mix math here (precomputed) -> short, pipelined load chains.
// Phase B: out[g][h][a][:] = 2*ab + (b==0 ? virt : lds), NT stores.
// ---------------------------------------------------------------------------
__global__ __launch_bounds__(256) void mixout_kernel(
    const float* __restrict__ attn_bias,    // [G][129][129]
    const int*   __restrict__ spatial_pos,  // [G*N*N]
    const float* __restrict__ spe,          // [512][H]
    const float* __restrict__ virt,         // [H]
    const int*   __restrict__ slot,         // [G*N*N][MAXD]
    const unsigned char* __restrict__ flags,// [G*N*N]
    const unsigned short* __restrict__ mixede, // [d][NE][H] bf16
    float* __restrict__ out) {              // [G][H][129][129]
  __shared__ float lds_val[N_ * 33];        // padded transpose tile
  __shared__ float lds_virt[H_];

  int blk = blockIdx.x;
  int g = blk / NP1_;
  int a = blk - g * NP1_;
  int tid = threadIdx.x;

  if (tid < H_) lds_virt[tid] = virt[tid];

  const float* ab = attn_bias + (g * NP1_ + a) * NP1_;

  if (a == 0) {
    __syncthreads();
    for (int t = tid; t < H_ * NP1_; t += 256) {
      int h = t / NP1_;
      int b = t - h * NP1_;
      __builtin_nontemporal_store(
          2.f * ab[b] + lds_virt[h],
          &out[((g * H_ + h) * NP1_) * NP1_ + b]);
    }
    return;
  }

  int gi = g * N_ + (a - 1);
  const int*           sp_row   = spatial_pos + (size_t)gi * N_;
  const unsigned char* fl_row   = flags + (size_t)gi * N_;
  const int*           slot_row = slot + (size_t)gi * N_ * MAXD_;

  int hw = tid >> 5;    // half-wave 0..7
  int h  = tid & 31;    // head

  // phase A: 16 cells per half-wave, 4-cell unrolled batches
  for (int it0 = 0; it0 < 16; it0 += 4) {
    int   sv[4];
    float acc[4] = {0.f, 0.f, 0.f, 0.f};
#pragma unroll
    for (int u = 0; u < 4; ++u)
      sv[u] = sp_row[hw * 16 + it0 + u];          // uniform, L1
#pragma unroll
    for (int u = 0; u < 4; ++u) {
      int j = hw * 16 + it0 + u;
      if (fl_row[j]) {                            // half-wave-uniform
        const int* sr = slot_row + j * MAXD_;
        int m[MAXD_];
#pragma unroll
        for (int d = 0; d < MAXD_; ++d) m[d] = sr[d];
#pragma unroll
        for (int d = 0; d < MAXD_; ++d) {
          if (m[d]) {
            acc[u] += bf2f(mixede[((size_t)d * NE_ + (m[d] - 1)) * H_ + h]);
          }
        }
      }
    }
#pragma unroll
    for (int u = 0; u < 4; ++u) {
      int j = hw * 16 + it0 + u;
      int s = sv[u];
      int s2 = (s == 0) ? 1 : s;
      s2 = (s2 > 1) ? s2 - 1 : s2;
      s2 = (s2 > MAXD_) ? MAXD_ : s2;
      float inv = (s2 == 1) ? 1.0f
                : (s2 == 2) ? 0.5f
                : (s2 == 3) ? (1.0f / 3.0f)
                : (s2 == 4) ? 0.25f : 0.2f;
      lds_val[j * 33 + h] = spe[s * H_ + h] + acc[u] * inv;
    }
  }
  __syncthreads();

  // phase B: transposed LDS reads (2-way max = free), NT coalesced stores
  for (int t = tid; t < H_ * NP1_; t += 256) {
    int h2 = t / NP1_;
    int b  = t - h2 * NP1_;
    float val = 2.f * ab[b];
    val += (b == 0) ? lds_virt[h2] : lds_val[(b - 1) * 33 + h2];
    __builtin_nontemporal_store(
        val, &out[((g * H_ + h2) * NP1_ + a) * NP1_ + b]);
  }
}

// ---------------------------------------------------------------------------
extern "C" void kernel_launch(void* const* d_in, const int* in_sizes, int n_in,
                              void* d_out, int out_size, void* d_ws, size_t ws_size,
                              hipStream_t stream) {
  const float* attn_bias   = (const float*)d_in[0];
  const int*   spatial_pos = (const int*)d_in[1];
  const int*   edge_index  = (const int*)d_in[2];
  const float* edge_attr   = (const float*)d_in[3];
  const int*   path_index  = (const int*)d_in[4];
  const float* edge_enc_w  = (const float*)d_in[5];
  const float* spe         = (const float*)d_in[6];
  const float* virt        = (const float*)d_in[7];
  const float* edge_dis    = (const float*)d_in[8];
  float* out = (float*)d_out;

  const size_t SLOT_ELEMS = (size_t)G_ * N_ * N_ * MAXD_;  // 2.62M ints
  const size_t MAP_ELEMS  = (size_t)G_ * N_ * N_;          // 512K ints
  const size_t FLAG_INTS  = (size_t)G_ * N_ * N_ / 4;      // 512KB as ints
  const size_t EAV_ELEMS  = (size_t)NE_ * H_;              // 2.1M floats

  int*            slot     = (int*)d_ws;
  int*            edge_map = slot + SLOT_ELEMS;
  unsigned char*  flags    = (unsigned char*)(edge_map + MAP_ELEMS);
  float*          eaval    = (float*)(edge_map + MAP_ELEMS + FLAG_INTS);
  unsigned short* mixede   = (unsigned short*)(eaval + EAV_ELEMS);   // 21MB

  // zero slot + edge_map + flags (13.1MB) with a streaming fill kernel
  {
    int n16 = (int)((SLOT_ELEMS + MAP_ELEMS + FLAG_INTS) * sizeof(int) / 16);
    zero_fill_kernel<<<1024, 256, 0, stream>>>((uint4*)d_ws, n16);
  }

  // edge encoder + map
  edge_encode_kernel<<<(NE_ * H_ + 255) / 256, 256, 0, stream>>>(
      edge_attr, edge_index, edge_enc_w, eaval, edge_map);
  // destination-organized path scatter (+ per-cell flag)
  path_scatter_kernel<<<NPTH_ / 256, 256, 0, stream>>>(
      path_index, edge_map, slot, flags);
  // dense (e,d) mix precompute -> bf16 mixede
  mix_edge_kernel<<<(MAXD_ * NE_) / 256, 256, 0, stream>>>(
      eaval, edge_dis, mixede);
  // fused fold + transpose + assembly
  mixout_kernel<<<G_ * NP1_, 256, 0, stream>>>(
      attn_bias, spatial_pos, spe, virt, slot, flags, mixede, out);
}

// Round 14
// 92.651 us; speedup vs baseline: 1.9943x; 1.3110x over previous
//
#include <hip/hip_runtime.h>

#define G_    32
#define N_    128
#define NP1_  129
#define H_    32
#define EAD_  16
#define MAXD_ 5
#define NE_   65536
#define NPTH_ 1048576

// ---------------------------------------------------------------------------
// Kernel 0: fast zero-fill. r12 profile showed the runtime's
// fillBufferAligned at 324 GB/s / 8.5% occupancy (~40us for 13MB); this
// grid-stride uint4 fill streams at ~4TB/s (~3us).
// ---------------------------------------------------------------------------
__global__ __launch_bounds__(256) void zero_fill_kernel(
    uint4* __restrict__ dst, int n16) {
  int idx = blockIdx.x * blockDim.x + threadIdx.x;
  int stride = gridDim.x * blockDim.x;
  const uint4 z = make_uint4(0u, 0u, 0u, 0u);
  for (int i = idx; i < n16; i += stride) dst[i] = z;
}

// ---------------------------------------------------------------------------
// Kernel 1: edge encoder into compact eaval[NE][H]; edge_map[(g,i,j)] = e+1.
// one thread per (edge, head); 32 consecutive threads write 128B contiguous.
// ---------------------------------------------------------------------------
__global__ __launch_bounds__(256) void edge_encode_kernel(
    const float* __restrict__ edge_attr,    // [NE][16]
    const int*   __restrict__ edge_index,   // [3][NE]
    const float* __restrict__ edge_enc_w,   // [H][16]
    float*       __restrict__ eaval,        // [NE][H]
    int*         __restrict__ edge_map) {   // [G][N][N], e+1 (0 = empty)
  int t = blockIdx.x * blockDim.x + threadIdx.x;
  if (t >= NE_ * H_) return;
  int e = t >> 5;
  int h = t & 31;
  const float* ea = edge_attr + e * EAD_;
  const float* w  = edge_enc_w + h * EAD_;
  float s = 0.f;
#pragma unroll
  for (int k = 0; k < EAD_; ++k) s += ea[k] * w[k];
  eaval[t] = s;
  if (h == 0) {
    int g = edge_index[e];
    int i = edge_index[NE_ + e];
    int j = edge_index[2 * NE_ + e];
    edge_map[(g * N_ + i) * N_ + j] = e + 1;
  }
}

// ---------------------------------------------------------------------------
// Kernel 2: destination-organized path scatter. 1 thread per path; probe
// edge_map first (3 coalesced streams + 1 random 4B in 2MB L2); load the
// destination components ONLY on hit (12.5%) — saves ~8MB of fetch.
// Destinations unique -> plain stores.
// ---------------------------------------------------------------------------
__global__ __launch_bounds__(256) void path_scatter_kernel(
    const int* __restrict__ path_index,     // [6][NPTH]
    const int* __restrict__ edge_map,       // [G][N][N]
    int*       __restrict__ slot) {         // [G*N*N][MAXD], e+1 (0 empty)
  int p = blockIdx.x * blockDim.x + threadIdx.x;
  int pg = path_index[p];
  int ps = path_index[4 * NPTH_ + p];
  int pt = path_index[5 * NPTH_ + p];
  int m = edge_map[(pg * N_ + ps) * N_ + pt];
  if (m) {
    int pi = path_index[NPTH_ + p];
    int pj = path_index[2 * NPTH_ + p];
    int pd = path_index[3 * NPTH_ + p];
    slot[((size_t)(pg * N_ + pi) * N_ + pj) * MAXD_ + pd] = m;
  }
}

// ---------------------------------------------------------------------------
// Kernel 3 (fused, r7-exact): queue-based per-row mix + final assembly.
// One block per (g, a) row.
// Phase 0: 640 slot ints read COALESCED by 256 threads; hits (~32) pushed
//          to an LDS queue packed as (j<<19 | d<<16 | e).
// Phase A: 8 lane-groups drain the queue; per item one uniform eaval row
//          (8 indep dwordx4, L2/L3) x Wd (L1) -> LDS float atomicAdd into
//          lds_val[j*33+lane] (2-way on wave64 = free).
// Phase A2: val[j][h] = spe[sp[j]][h] + val[j][h]*inv(j)  (coalesced spe).
// Phase B: write out[g][h][a][:] reading LDS transposed (stride 33).
// ---------------------------------------------------------------------------
__global__ __launch_bounds__(256) void output_fused_kernel(
    const float* __restrict__ attn_bias,    // [G][129][129]
    const int*   __restrict__ spatial_pos,  // [G][N][N]
    const float* __restrict__ spe,          // [512][H]
    const float* __restrict__ virt,         // [H]
    const int*   __restrict__ slot,         // [G][N][N][MAXD]
    const float* __restrict__ eaval,        // [NE][H]
    const float* __restrict__ Wdis,         // edge_dis_emb flat [d][h][k]
    float*       __restrict__ out) {        // [G][H][129][129]
  __shared__ float lds_val[N_ * 33];        // padded: conflict-free transpose
  __shared__ float lds_virt[H_];
  __shared__ int   q[N_ * MAXD_];
  __shared__ int   q_cnt;

  int blk = blockIdx.x;
  int g = blk / NP1_;
  int a = blk - g * NP1_;
  int tid = threadIdx.x;

  if (tid < H_) lds_virt[tid] = virt[tid];

  const float* ab = attn_bias + (g * NP1_ + a) * NP1_;

  if (a == 0) {
    __syncthreads();
    for (int t = tid; t < H_ * NP1_; t += 256) {
      int h = t / NP1_;
      int b = t - h * NP1_;
      out[((g * H_ + h) * NP1_) * NP1_ + b] = 2.f * ab[b] + lds_virt[h];
    }
    return;
  }

  int i = a - 1;
  const int* sp_row   = spatial_pos + (g * N_ + i) * N_;
  const int* slot_row = slot + (size_t)((g * N_ + i) * N_) * MAXD_;

  // zero the accumulator tile; init queue
  for (int t = tid; t < N_ * 33; t += 256) lds_val[t] = 0.f;
  if (tid == 0) q_cnt = 0;
  __syncthreads();

  // phase 0: coalesced slot scan -> LDS queue (640 ints, 2.5 loads/thread)
  for (int f = tid; f < N_ * MAXD_; f += 256) {
    int m = slot_row[f];
    if (m) {
      int j = f / MAXD_;
      int d = f - j * MAXD_;
      int idx = atomicAdd(&q_cnt, 1);             // LDS atomic
      q[idx] = (j << 19) | (d << 16) | (m - 1);
    }
  }
  __syncthreads();
  int cnt = q_cnt;

  // phase A: 8 lane-groups drain the queue (~4 items each)
  int grp  = tid >> 5;
  int lane = tid & 31;
  for (int s = grp; s < cnt; s += 8) {
    int ent = q[s];
    int j = ent >> 19;
    int d = (ent >> 16) & 7;
    int e = ent & 0xFFFF;
    const float* ea = eaval + (size_t)e * H_;     // group-uniform row
    const float* Wd = Wdis + d * (H_ * H_);       // 20KB total, L1-resident
    float v0 = 0.f, v1 = 0.f, v2 = 0.f, v3 = 0.f;
#pragma unroll
    for (int h = 0; h < H_; h += 4) {
      v0 += ea[h + 0] * Wd[(h + 0) * H_ + lane];
      v1 += ea[h + 1] * Wd[(h + 1) * H_ + lane];
      v2 += ea[h + 2] * Wd[(h + 2) * H_ + lane];
      v3 += ea[h + 3] * Wd[(h + 3) * H_ + lane];
    }
    atomicAdd(&lds_val[j * 33 + lane], (v0 + v1) + (v2 + v3));
  }
  __syncthreads();

  // phase A2: add spatial embedding, apply path-length normalizer
  for (int t = tid; t < N_ * H_; t += 256) {
    int j = t >> 5;
    int h = t & 31;
    int s = sp_row[j];                      // group-uniform
    int s2 = (s == 0) ? 1 : s;
    s2 = (s2 > 1) ? s2 - 1 : s2;
    s2 = (s2 > MAXD_) ? MAXD_ : s2;
    float inv = (s2 == 1) ? 1.0f
              : (s2 == 2) ? 0.5f
              : (s2 == 3) ? (1.0f / 3.0f)
              : (s2 == 4) ? 0.25f : 0.2f;
    lds_val[j * 33 + h] = spe[s * H_ + h] + lds_val[j * 33 + h] * inv;
  }
  __syncthreads();

  // phase B: pure write loop; LDS transposed reads, conflict-free
  for (int t = tid; t < H_ * NP1_; t += 256) {
    int h = t / NP1_;
    int b = t - h * NP1_;
    float val = 2.f * ab[b];
    if (b == 0) {
      val += lds_virt[h];
    } else {
      val += lds_val[(b - 1) * 33 + h];
    }
    out[((g * H_ + h) * NP1_ + a) * NP1_ + b] = val;
  }
}

// ---------------------------------------------------------------------------
extern "C" void kernel_launch(void* const* d_in, const int* in_sizes, int n_in,
                              void* d_out, int out_size, void* d_ws, size_t ws_size,
                              hipStream_t stream) {
  const float* attn_bias   = (const float*)d_in[0];
  const int*   spatial_pos = (const int*)d_in[1];
  const int*   edge_index  = (const int*)d_in[2];
  const float* edge_attr   = (const float*)d_in[3];
  const int*   path_index  = (const int*)d_in[4];
  const float* edge_enc_w  = (const float*)d_in[5];
  const float* spe         = (const float*)d_in[6];
  const float* virt        = (const float*)d_in[7];
  const float* edge_dis    = (const float*)d_in[8];
  float* out = (float*)d_out;

  const size_t SLOT_ELEMS = (size_t)G_ * N_ * N_ * MAXD_;  // 2.62M ints
  const size_t MAP_ELEMS  = (size_t)G_ * N_ * N_;          // 512K ints

  int*   slot     = (int*)d_ws;
  int*   edge_map = slot + SLOT_ELEMS;
  float* eaval    = (float*)(edge_map + MAP_ELEMS);

  // zero slot + edge_map (contiguous, 12.6MB) with the streaming fill
  {
    int n16 = (int)((SLOT_ELEMS + MAP_ELEMS) * sizeof(int) / 16);
    zero_fill_kernel<<<1024, 256, 0, stream>>>((uint4*)d_ws, n16);
  }

  // edge encoder + map
  edge_encode_kernel<<<(NE_ * H_ + 255) / 256, 256, 0, stream>>>(
      edge_attr, edge_index, edge_enc_w, eaval, edge_map);
  // destination-organized path scatter (conditional tail loads)
  path_scatter_kernel<<<NPTH_ / 256, 256, 0, stream>>>(
      path_index, edge_map, slot);
  // fused queue mix + final output (r7-exact)
  output_fused_kernel<<<G_ * NP1_, 256, 0, stream>>>(
      attn_bias, spatial_pos, spe, virt, slot, eaval, edge_dis, out);
}